// Round 11
// baseline (47.507 us; speedup 1.0000x reference)
//
#include <hip/hip_runtime.h>

#define IMG 1024
#define RH  32               // output rows per band
#define NW  4                // waves per block (256 threads, 4 cols/lane = 1024 cols)
#define NEG_INF (-__builtin_inff())
#define PMASK 0x01010101u    // bit0 of each byte = current-row bit plane, byte i = col i of lane

// ---- DPP lane+-1 exchange (wave_shr:1 = 0x138, wave_shl:1 = 0x130; gfx9-lineage) ----
__device__ __forceinline__ unsigned dpp_shr1_u(unsigned x) {   // lane i <- lane i-1 (lane0 -> 0)
    return (unsigned)__builtin_amdgcn_update_dpp(0, (int)x, 0x138, 0xf, 0xf, true);
}
__device__ __forceinline__ unsigned dpp_shl1_u(unsigned x) {   // lane i <- lane i+1 (lane63 -> 0)
    return (unsigned)__builtin_amdgcn_update_dpp(0, (int)x, 0x130, 0xf, 0xf, true);
}
__device__ __forceinline__ float dpp_shr1_f(float x) { return __uint_as_float(dpp_shr1_u(__float_as_uint(x))); }
__device__ __forceinline__ float dpp_shl1_f(float x) { return __uint_as_float(dpp_shl1_u(__float_as_uint(x))); }

__device__ __forceinline__ float max3f(float a, float b, float c) { return fmaxf(fmaxf(a, b), c); }

__device__ __forceinline__ float4 vmax3(float4 a, float4 b, float4 c) {
    return make_float4(max3f(a.x,b.x,c.x), max3f(a.y,b.y,c.y),
                       max3f(a.z,b.z,c.z), max3f(a.w,b.w,c.w));
}

__device__ __forceinline__ float4 hmax3(float4 f, float Lin, float Rin, bool l0, bool l63) {
    float sl = dpp_shr1_f(f.w);
    float sr = dpp_shl1_f(f.x);
    float L = l0 ? Lin : sl;
    float R = l63 ? Rin : sr;
    return make_float4(max3f(L,   f.x, f.y), max3f(f.x, f.y, f.z),
                       max3f(f.y, f.z, f.w), max3f(f.z, f.w, R));
}

__device__ __forceinline__ unsigned hor3(unsigned p, unsigned Lbit, unsigned Rbit, bool l0, bool l63) {
    unsigned sl = dpp_shr1_u(p);
    unsigned sr = dpp_shl1_u(p);
    unsigned L = l0 ? Lbit : ((sl >> 24) & 1u);
    unsigned R = l63 ? Rbit : (sr & 1u);
    return ((p | (p << 8) | (p >> 8)) & PMASK) | L | (R << 24);
}

// equality plane, unguarded (row-validity applied by scalar rvm AND outside)
__device__ __forceinline__ unsigned cmp_plane(float4 a, float4 m) {
    return (a.x == m.x ? 0x1u : 0u) | (a.y == m.y ? 0x100u : 0u) |
           (a.z == m.z ? 0x10000u : 0u) | (a.w == m.w ? 0x1000000u : 0u);
}

// plane already AND'd with row-validity: bit set -> real suppressed pixel -> 0
__device__ __forceinline__ float4 supsel(unsigned plane, float4 v) {
    return make_float4(((plane >>  0) & 1u) ? 0.f : v.x,
                       ((plane >>  8) & 1u) ? 0.f : v.y,
                       ((plane >> 16) & 1u) ? 0.f : v.z,
                       ((plane >> 24) & 1u) ? 0.f : v.w);
}

__device__ __forceinline__ float bsel(unsigned bits, int sh, float v) {
    return ((bits >> sh) & 1u) ? v : 0.f;
}

// scalar (wave-uniform) per-row validity mask
__device__ __forceinline__ unsigned vmask(int r, int lmax) {
    return ((unsigned)r < (unsigned)lmax) ? PMASK : 0u;
}

// One pipeline step; K = 0..3 within unrolled group, PAR = (sb+K)&1 (compile-time).
#define STEP(K, PAR) do {                                                               \
    const int s_ = sb + (K);                                                            \
    const float4 pLp = edgeR[(PAR)^1][w];                                               \
    const float4 pRp = edgeL[(PAR)^1][w + 2];                                           \
    const unsigned pLb = __float_as_uint(pLp.w);                                        \
    const unsigned pRb = __float_as_uint(pRp.w);                                        \
    /* S3: hmax(scores) row s-1 */                                                      \
    HV[(K)+2] = hmax3(H[9+(K)], pLp.x, pRp.x, l0, l63);                                 \
    /* S4: m0 row s-2 */                                                                \
    float4 vm0 = vmax3(HV[(K)+2], HV[(K)+1], HV[(K)]);                                  \
    unsigned m0n = cmp_plane(H[8+(K)], vm0) & vmask(s_ - 2, lmax);                      \
    m0h = ((m0h << 1) & ~PMASK) | m0n;                                                  \
    /* S5: hm0 row s-3 */                                                               \
    unsigned hm0n = hor3((m0h >> 1) & PMASK, pLb & 1u, pRb & 1u, l0, l63);              \
    hm0h = ((hm0h << 1) & ~PMASK) | hm0n;                                               \
    /* S6: supp1 row s-4 */                                                             \
    unsigned s1n = (hm0h | (hm0h >> 1) | (hm0h >> 2)) & PMASK;                          \
    s1h = ((s1h << 1) & ~PMASK) | s1n;                                                  \
    /* S7: ss1 row s-4 */                                                               \
    SS1[(K)+1] = supsel(s1n & vmask(s_ - 4, lmax), H[6+(K)]);                           \
    /* S8: hmax(ss1) row s-5 */                                                         \
    H1[(K)+2] = hmax3(SS1[(K)], pLp.y, pRp.y, l0, l63);                                 \
    /* S9: mask1 row s-6 */                                                             \
    float4 vm1 = vmax3(H1[(K)+2], H1[(K)+1], H1[(K)]);                                  \
    unsigned s1l2 = (s1h >> 2) & PMASK;                                                 \
    unsigned rvm6 = vmask(s_ - 6, lmax);                                                \
    float4 ss16 = supsel(s1l2 & rvm6, H[4+(K)]);                                        \
    unsigned nm1 = cmp_plane(ss16, vm1) & rvm6;                                         \
    unsigned mk1n = ((m0h >> 4) & PMASK) | (nm1 & ~s1l2);                               \
    mk1h = ((mk1h << 1) & ~PMASK) | mk1n;                                               \
    /* S10: hm1 row s-7 */                                                              \
    unsigned hm1n = hor3((mk1h >> 1) & PMASK, (pLb >> 1) & 1u, (pRb >> 1) & 1u, l0, l63);\
    hm1h = ((hm1h << 1) & ~PMASK) | hm1n;                                               \
    /* S11: supp2 row s-8 */                                                            \
    unsigned s2n = (hm1h | (hm1h >> 1) | (hm1h >> 2)) & PMASK;                          \
    s2h = ((s2h << 1) & ~PMASK) | s2n;                                                  \
    /* S12: ss2 row s-8 */                                                              \
    SS2[(K)+1] = supsel(s2n & vmask(s_ - 8, lmax), H[2+(K)]);                           \
    /* S13: hmax(ss2) row s-9 */                                                        \
    H2[(K)+2] = hmax3(SS2[(K)], pLp.z, pRp.z, l0, l63);                                 \
    /* S14: mask2 + output row s-10 */                                                  \
    float4 vm2 = vmax3(H2[(K)+2], H2[(K)+1], H2[(K)]);                                  \
    unsigned s2l2 = (s2h >> 2) & PMASK;                                                 \
    unsigned rvm10 = vmask(s_ - 10, lmax);                                              \
    float4 ss210 = supsel(s2l2 & rvm10, H[(K)]);                                        \
    unsigned nm2 = cmp_plane(ss210, vm2) & rvm10;                                       \
    unsigned mk2 = ((mk1h >> 4) & PMASK) | (nm2 & ~s2l2);                               \
    const int srow = s_ - 10;                                                           \
    if (srow >= y0 && srow < yend) {                                                    \
        float4 vv = H[(K)];                                                             \
        outp4[(size_t)srow * (IMG/4) + tid] = make_float4(                              \
            bsel(mk2, 0, vv.x), bsel(mk2, 8, vv.y),                                     \
            bsel(mk2, 16, vv.z), bsel(mk2, 24, vv.w));                                  \
    }                                                                                   \
    unsigned bitsR = ((m0n >> 24) & 1u) | (((mk1n >> 24) & 1u) << 1);                   \
    unsigned bitsL = (m0n & 1u) | ((mk1n & 1u) << 1);                                   \
    if (l63) edgeR[(PAR)][w + 1] = make_float4(H[10+(K)].w, SS1[(K)+1].w, SS2[(K)+1].w, __uint_as_float(bitsR)); \
    if (l0)  edgeL[(PAR)][w + 1] = make_float4(H[10+(K)].x, SS1[(K)+1].x, SS2[(K)+1].x, __uint_as_float(bitsL)); \
    __syncthreads();                                                                    \
} while (0)

__global__ __launch_bounds__(256, 2)
void nms_sweep(const float* __restrict__ in, float* __restrict__ out)
{
    __shared__ float4 edgeR[2][NW + 2];
    __shared__ float4 edgeL[2][NW + 2];

    const int tid  = threadIdx.x;
    const int lane = tid & 63;
    const int w    = tid >> 6;
    const bool l0  = (lane == 0);
    const bool l63 = (lane == 63);
    const int y0   = (int)blockIdx.x * RH;
    const int yend = y0 + RH;
    const size_t base = (size_t)blockIdx.y * ((size_t)IMG * IMG);
    const int lmax = (yend + 5 < IMG) ? yend + 5 : IMG;

    const float4* inp4  = (const float4*)(in + base);
    float4*       outp4 = (float4*)(out + base);

    // init edge slots (both parities) to sentinel {-inf,-inf,-inf,bits=0}
    for (int i = tid; i < 2 * (NW + 2); i += 256) {
        int p = i & 1, sl = i >> 1;
        float4 s = make_float4(NEG_INF, NEG_INF, NEG_INF, __uint_as_float(0u));
        edgeR[p][sl] = s;
        edgeL[p][sl] = s;
    }

    const float4 ninf4 = make_float4(NEG_INF, NEG_INF, NEG_INF, NEG_INF);
    // H[i]  = scores row sb-10+i          (carried i=0..9, this group's rows i=10..13)
    // Hn[i] = NEXT group's rows (prefetch, consumed by rotate)
    float4 H[14], Hn[4], HV[6], SS1[5], H1[6], SS2[5], H2[6];
#pragma unroll
    for (int i = 0; i < 14; ++i) H[i] = ninf4;
#pragma unroll
    for (int i = 0; i < 6; ++i) { HV[i] = ninf4; H1[i] = ninf4; H2[i] = ninf4; }
#pragma unroll
    for (int i = 0; i < 5; ++i) { SS1[i] = ninf4; SS2[i] = ninf4; }
    unsigned m0h = 0, hm0h = 0, s1h = 0, mk1h = 0, hm1h = 0, s2h = 0;

    int sb = y0 - 5;   // y0 even -> sb odd -> PAR sequence per group: 1,0,1,0 (static)

    // prologue: load group 0's rows directly into H[10..13]
#pragma unroll
    for (int k = 0; k < 4; ++k) {
        const int r = sb + k;
        H[10 + k] = ((unsigned)r < (unsigned)lmax) ? inp4[(size_t)r * (IMG/4) + tid] : ninf4;
    }
    __syncthreads();

    for (int it = 0; it < 12; ++it) {
        // prefetch NEXT group's rows; first use is 4 steps away (~full group of VALU)
#pragma unroll
        for (int k = 0; k < 4; ++k) {
            const int r = sb + 4 + k;
            Hn[k] = ((unsigned)r < (unsigned)lmax) ? inp4[(size_t)r * (IMG/4) + tid] : ninf4;
        }

        STEP(0, 1);
        STEP(1, 0);
        STEP(2, 1);
        STEP(3, 0);

        // rotate state by 4 rows (static indices -> pure register renames/movs)
#pragma unroll
        for (int i = 0; i < 10; ++i) H[i] = H[i + 4];
        H[10] = Hn[0]; H[11] = Hn[1]; H[12] = Hn[2]; H[13] = Hn[3];
        HV[0] = HV[4];  HV[1] = HV[5];
        SS1[0] = SS1[4];
        H1[0] = H1[4];  H1[1] = H1[5];
        SS2[0] = SS2[4];
        H2[0] = H2[4];  H2[1] = H2[5];
        sb += 4;
    }
}

extern "C" void kernel_launch(void* const* d_in, const int* in_sizes, int n_in,
                              void* d_out, int out_size, void* d_ws, size_t ws_size,
                              hipStream_t stream) {
    const float* in = (const float*)d_in[0];
    float* out = (float*)d_out;
    const int batch = in_sizes[0] / (IMG * IMG);
    dim3 grid(IMG / RH, batch, 1);
    nms_sweep<<<grid, dim3(256, 1, 1), 0, stream>>>(in, out);
}

// Round 12
// 47.450 us; speedup vs baseline: 1.0012x; 1.0012x over previous
//
#include <hip/hip_runtime.h>

#define IMG 1024
#define RH  32               // output rows per band
#define NW  4                // waves per block (256 threads, 4 cols/lane = 1024 cols)
#define NEG_INF (-__builtin_inff())
#define PMASK 0x01010101u    // bit0 of each byte = current-row bit plane, byte i = col i of lane

// ---- DPP lane+-1 exchange (wave_shr:1 = 0x138, wave_shl:1 = 0x130; gfx9-lineage) ----
__device__ __forceinline__ unsigned dpp_shr1_u(unsigned x) {   // lane i <- lane i-1 (lane0 -> 0)
    return (unsigned)__builtin_amdgcn_update_dpp(0, (int)x, 0x138, 0xf, 0xf, true);
}
__device__ __forceinline__ unsigned dpp_shl1_u(unsigned x) {   // lane i <- lane i+1 (lane63 -> 0)
    return (unsigned)__builtin_amdgcn_update_dpp(0, (int)x, 0x130, 0xf, 0xf, true);
}
__device__ __forceinline__ float dpp_shr1_f(float x) { return __uint_as_float(dpp_shr1_u(__float_as_uint(x))); }
__device__ __forceinline__ float dpp_shl1_f(float x) { return __uint_as_float(dpp_shl1_u(__float_as_uint(x))); }

__device__ __forceinline__ float max3f(float a, float b, float c) { return fmaxf(fmaxf(a, b), c); }

__device__ __forceinline__ float4 vmax3(float4 a, float4 b, float4 c) {
    return make_float4(max3f(a.x,b.x,c.x), max3f(a.y,b.y,c.y),
                       max3f(a.z,b.z,c.z), max3f(a.w,b.w,c.w));
}

__device__ __forceinline__ float4 hmax3(float4 f, float Lin, float Rin, bool l0, bool l63) {
    float sl = dpp_shr1_f(f.w);
    float sr = dpp_shl1_f(f.x);
    float L = l0 ? Lin : sl;
    float R = l63 ? Rin : sr;
    return make_float4(max3f(L,   f.x, f.y), max3f(f.x, f.y, f.z),
                       max3f(f.y, f.z, f.w), max3f(f.z, f.w, R));
}

__device__ __forceinline__ unsigned hor3(unsigned p, unsigned Lbit, unsigned Rbit, bool l0, bool l63) {
    unsigned sl = dpp_shr1_u(p);
    unsigned sr = dpp_shl1_u(p);
    unsigned L = l0 ? Lbit : ((sl >> 24) & 1u);
    unsigned R = l63 ? Rbit : (sr & 1u);
    return ((p | (p << 8) | (p >> 8)) & PMASK) | L | (R << 24);
}

// equality plane, unguarded (row-validity applied by scalar rvm AND outside)
__device__ __forceinline__ unsigned cmp_plane(float4 a, float4 m) {
    return (a.x == m.x ? 0x1u : 0u) | (a.y == m.y ? 0x100u : 0u) |
           (a.z == m.z ? 0x10000u : 0u) | (a.w == m.w ? 0x1000000u : 0u);
}

// plane already AND'd with row-validity: bit set -> real suppressed pixel -> 0
__device__ __forceinline__ float4 supsel(unsigned plane, float4 v) {
    return make_float4(((plane >>  0) & 1u) ? 0.f : v.x,
                       ((plane >>  8) & 1u) ? 0.f : v.y,
                       ((plane >> 16) & 1u) ? 0.f : v.z,
                       ((plane >> 24) & 1u) ? 0.f : v.w);
}

__device__ __forceinline__ float bsel(unsigned bits, int sh, float v) {
    return ((bits >> sh) & 1u) ? v : 0.f;
}

// scalar (wave-uniform) per-row validity mask
__device__ __forceinline__ unsigned vmask(int r, int lmax) {
    return ((unsigned)r < (unsigned)lmax) ? PMASK : 0u;
}

// LDS-only barrier: orders ds_write -> (other waves') ds_read WITHOUT draining
// vmcnt — global prefetch loads stay in flight across it (unlike __syncthreads,
// which emits s_waitcnt vmcnt(0) lgkmcnt(0) and kills the pipeline).
#define LDS_BARRIER() do {                                   \
    __builtin_amdgcn_sched_barrier(0);                       \
    asm volatile("s_waitcnt lgkmcnt(0)" ::: "memory");       \
    __builtin_amdgcn_s_barrier();                            \
    __builtin_amdgcn_sched_barrier(0);                       \
} while (0)

// One pipeline step; K = 0..3 within unrolled group, PAR = (sb+K)&1 (compile-time).
#define STEP(K, PAR) do {                                                               \
    const int s_ = sb + (K);                                                            \
    const float4 pLp = edgeR[(PAR)^1][w];                                               \
    const float4 pRp = edgeL[(PAR)^1][w + 2];                                           \
    const unsigned pLb = __float_as_uint(pLp.w);                                        \
    const unsigned pRb = __float_as_uint(pRp.w);                                        \
    /* S3: hmax(scores) row s-1 */                                                      \
    HV[(K)+2] = hmax3(H[9+(K)], pLp.x, pRp.x, l0, l63);                                 \
    /* S4: m0 row s-2 */                                                                \
    float4 vm0 = vmax3(HV[(K)+2], HV[(K)+1], HV[(K)]);                                  \
    unsigned m0n = cmp_plane(H[8+(K)], vm0) & vmask(s_ - 2, lmax);                      \
    m0h = ((m0h << 1) & ~PMASK) | m0n;                                                  \
    /* S5: hm0 row s-3 */                                                               \
    unsigned hm0n = hor3((m0h >> 1) & PMASK, pLb & 1u, pRb & 1u, l0, l63);              \
    hm0h = ((hm0h << 1) & ~PMASK) | hm0n;                                               \
    /* S6: supp1 row s-4 */                                                             \
    unsigned s1n = (hm0h | (hm0h >> 1) | (hm0h >> 2)) & PMASK;                          \
    s1h = ((s1h << 1) & ~PMASK) | s1n;                                                  \
    /* S7: ss1 row s-4 */                                                               \
    SS1[(K)+1] = supsel(s1n & vmask(s_ - 4, lmax), H[6+(K)]);                           \
    /* S8: hmax(ss1) row s-5 */                                                         \
    H1[(K)+2] = hmax3(SS1[(K)], pLp.y, pRp.y, l0, l63);                                 \
    /* S9: mask1 row s-6 */                                                             \
    float4 vm1 = vmax3(H1[(K)+2], H1[(K)+1], H1[(K)]);                                  \
    unsigned s1l2 = (s1h >> 2) & PMASK;                                                 \
    unsigned rvm6 = vmask(s_ - 6, lmax);                                                \
    float4 ss16 = supsel(s1l2 & rvm6, H[4+(K)]);                                        \
    unsigned nm1 = cmp_plane(ss16, vm1) & rvm6;                                         \
    unsigned mk1n = ((m0h >> 4) & PMASK) | (nm1 & ~s1l2);                               \
    mk1h = ((mk1h << 1) & ~PMASK) | mk1n;                                               \
    /* S10: hm1 row s-7 */                                                              \
    unsigned hm1n = hor3((mk1h >> 1) & PMASK, (pLb >> 1) & 1u, (pRb >> 1) & 1u, l0, l63);\
    hm1h = ((hm1h << 1) & ~PMASK) | hm1n;                                               \
    /* S11: supp2 row s-8 */                                                            \
    unsigned s2n = (hm1h | (hm1h >> 1) | (hm1h >> 2)) & PMASK;                          \
    s2h = ((s2h << 1) & ~PMASK) | s2n;                                                  \
    /* S12: ss2 row s-8 */                                                              \
    SS2[(K)+1] = supsel(s2n & vmask(s_ - 8, lmax), H[2+(K)]);                           \
    /* S13: hmax(ss2) row s-9 */                                                        \
    H2[(K)+2] = hmax3(SS2[(K)], pLp.z, pRp.z, l0, l63);                                 \
    /* S14: mask2 + output row s-10 */                                                  \
    float4 vm2 = vmax3(H2[(K)+2], H2[(K)+1], H2[(K)]);                                  \
    unsigned s2l2 = (s2h >> 2) & PMASK;                                                 \
    unsigned rvm10 = vmask(s_ - 10, lmax);                                              \
    float4 ss210 = supsel(s2l2 & rvm10, H[(K)]);                                        \
    unsigned nm2 = cmp_plane(ss210, vm2) & rvm10;                                       \
    unsigned mk2 = ((mk1h >> 4) & PMASK) | (nm2 & ~s2l2);                               \
    const int srow = s_ - 10;                                                           \
    if (srow >= y0 && srow < yend) {                                                    \
        float4 vv = H[(K)];                                                             \
        outp4[(size_t)srow * (IMG/4) + tid] = make_float4(                              \
            bsel(mk2, 0, vv.x), bsel(mk2, 8, vv.y),                                     \
            bsel(mk2, 16, vv.z), bsel(mk2, 24, vv.w));                                  \
    }                                                                                   \
    unsigned bitsR = ((m0n >> 24) & 1u) | (((mk1n >> 24) & 1u) << 1);                   \
    unsigned bitsL = (m0n & 1u) | ((mk1n & 1u) << 1);                                   \
    if (l63) edgeR[(PAR)][w + 1] = make_float4(H[10+(K)].w, SS1[(K)+1].w, SS2[(K)+1].w, __uint_as_float(bitsR)); \
    if (l0)  edgeL[(PAR)][w + 1] = make_float4(H[10+(K)].x, SS1[(K)+1].x, SS2[(K)+1].x, __uint_as_float(bitsL)); \
    LDS_BARRIER();                                                                      \
} while (0)

__global__ __launch_bounds__(256, 2)
void nms_sweep(const float* __restrict__ in, float* __restrict__ out)
{
    __shared__ float4 edgeR[2][NW + 2];
    __shared__ float4 edgeL[2][NW + 2];

    const int tid  = threadIdx.x;
    const int lane = tid & 63;
    const int w    = tid >> 6;
    const bool l0  = (lane == 0);
    const bool l63 = (lane == 63);
    const int y0   = (int)blockIdx.x * RH;
    const int yend = y0 + RH;
    const size_t base = (size_t)blockIdx.y * ((size_t)IMG * IMG);
    const int lmax = (yend + 5 < IMG) ? yend + 5 : IMG;

    const float4* inp4  = (const float4*)(in + base);
    float4*       outp4 = (float4*)(out + base);

    // init edge slots (both parities) to sentinel {-inf,-inf,-inf,bits=0}
    for (int i = tid; i < 2 * (NW + 2); i += 256) {
        int p = i & 1, sl = i >> 1;
        float4 s = make_float4(NEG_INF, NEG_INF, NEG_INF, __uint_as_float(0u));
        edgeR[p][sl] = s;
        edgeL[p][sl] = s;
    }

    const float4 ninf4 = make_float4(NEG_INF, NEG_INF, NEG_INF, NEG_INF);
    // H[i]  = scores row sb-10+i          (carried i=0..9, this group's rows i=10..13)
    // Hn[i] = NEXT group's rows (prefetch; stays in flight across LDS_BARRIERs)
    float4 H[14], Hn[4], HV[6], SS1[5], H1[6], SS2[5], H2[6];
#pragma unroll
    for (int i = 0; i < 14; ++i) H[i] = ninf4;
#pragma unroll
    for (int i = 0; i < 6; ++i) { HV[i] = ninf4; H1[i] = ninf4; H2[i] = ninf4; }
#pragma unroll
    for (int i = 0; i < 5; ++i) { SS1[i] = ninf4; SS2[i] = ninf4; }
    unsigned m0h = 0, hm0h = 0, s1h = 0, mk1h = 0, hm1h = 0, s2h = 0;

    int sb = y0 - 5;   // y0 even -> sb odd -> PAR sequence per group: 1,0,1,0 (static)

    // prologue: load group 0's rows directly into H[10..13]
#pragma unroll
    for (int k = 0; k < 4; ++k) {
        const int r = sb + k;
        H[10 + k] = ((unsigned)r < (unsigned)lmax) ? inp4[(size_t)r * (IMG/4) + tid] : ninf4;
    }
    __syncthreads();   // once: edge-init visibility (full drain is fine here)

    for (int it = 0; it < 12; ++it) {
        // prefetch NEXT group's rows; consumed 4+ steps later, loads no longer
        // drained at barriers -> ~1200 cyc of VALU covers the ~900 cyc HBM latency
#pragma unroll
        for (int k = 0; k < 4; ++k) {
            const int r = sb + 4 + k;
            Hn[k] = ((unsigned)r < (unsigned)lmax) ? inp4[(size_t)r * (IMG/4) + tid] : ninf4;
        }

        STEP(0, 1);
        STEP(1, 0);
        STEP(2, 1);
        STEP(3, 0);

        // rotate state by 4 rows (static indices -> pure register renames/movs)
#pragma unroll
        for (int i = 0; i < 10; ++i) H[i] = H[i + 4];
        H[10] = Hn[0]; H[11] = Hn[1]; H[12] = Hn[2]; H[13] = Hn[3];
        HV[0] = HV[4];  HV[1] = HV[5];
        SS1[0] = SS1[4];
        H1[0] = H1[4];  H1[1] = H1[5];
        SS2[0] = SS2[4];
        H2[0] = H2[4];  H2[1] = H2[5];
        sb += 4;
    }
}

extern "C" void kernel_launch(void* const* d_in, const int* in_sizes, int n_in,
                              void* d_out, int out_size, void* d_ws, size_t ws_size,
                              hipStream_t stream) {
    const float* in = (const float*)d_in[0];
    float* out = (float*)d_out;
    const int batch = in_sizes[0] / (IMG * IMG);
    dim3 grid(IMG / RH, batch, 1);
    nms_sweep<<<grid, dim3(256, 1, 1), 0, stream>>>(in, out);
}